// Round 5
// baseline (134.223 us; speedup 1.0000x reference)
//
#include <hip/hip_runtime.h>
#include <math.h>

#define TW 32
#define TH 64
#define HR2 (TH + 10)       // 74 intermediate rows
#define NTASK (HR2 * 4)     // 296 phase-1 tasks (row, 8-col chunk)
#define IMG_W 512
#define OUT_W 502           // 512 - 11 + 1
#define CH_STRIDE (3 * IMG_W * IMG_W)

// Tile: 32 wide x 64 tall outputs per block, grid 16 x 8 x 16 = 2048 blocks.
// Phase 1: 296 tasks (strided over 256 threads): horizontal 11-tap for one of
//          74 rows x 8-col chunk, loading a 20-float span from global
//          (float4), writing 5 intermediate fields to LDS as float4.
// Phase 2: 256 threads = 32 cols x 8 strips of 8 rows: each reads 18 rows x 5
//          fields ONCE (register accumulation; 2.25 reads/output vs 3.5 in R3),
//          applies SSIM, block-reduces, one atomicAdd into d_out.
__global__ __launch_bounds__(256) void ssim_main_kernel(
    const float* __restrict__ sr_img,
    const float* __restrict__ hr_img,
    float* __restrict__ out)
{
    __shared__ float hf[5][HR2][TW];   // m1, m2, x2, y2, xy  (47360 B -> 3 blk/CU)
    __shared__ float red[4];

    const int t  = threadIdx.x;
    const int x0 = blockIdx.x * TW;
    const int y0 = blockIdx.y * TH;
    const int b  = blockIdx.z;

    // 1D Gaussian (separable window); same numerics as reference
    float w[11];
    {
        float s = 0.f;
#pragma unroll
        for (int i = 0; i < 11; ++i) {
            float d = (float)(i - 5);
            w[i] = expf(-d * d / 4.5f);
            s += w[i];
        }
        float inv = 1.f / s;
#pragma unroll
        for (int i = 0; i < 11; ++i) w[i] *= inv;
    }

    const float* __restrict__ hrp = hr_img + (size_t)b * CH_STRIDE;  // channel 0
    const float* __restrict__ srp = sr_img + (size_t)b * CH_STRIDE;

    // ---------- Phase 1: horizontal 11-tap, direct from global ----------
    for (int task = t; task < NTASK; task += 256) {
        int r  = task >> 2;       // 0..73
        int c0 = (task & 3) * 8;  // 0,8,16,24
        int gy = y0 + r; if (gy > IMG_W - 1) gy = IMG_W - 1;
        // 16B-aligned; right-edge spill stays inside the allocation (reads
        // into channel 1 at worst) and only feeds discarded outputs.
        const float4* hrow = (const float4*)(hrp + (size_t)gy * IMG_W + x0 + c0);
        const float4* srow = (const float4*)(srp + (size_t)gy * IMG_W + x0 + c0);

        float h[20], s[20];
#pragma unroll
        for (int q = 0; q < 5; ++q) {
            float4 va = hrow[q];
            h[4*q] = va.x; h[4*q+1] = va.y; h[4*q+2] = va.z; h[4*q+3] = va.w;
            float4 vb = srow[q];
            s[4*q] = vb.x; s[4*q+1] = vb.y; s[4*q+2] = vb.z; s[4*q+3] = vb.w;
        }

        float m1[8], m2[8], x2[8], y2[8], xy[8];
#pragma unroll
        for (int j = 0; j < 8; ++j) { m1[j]=0.f; m2[j]=0.f; x2[j]=0.f; y2[j]=0.f; xy[j]=0.f; }
#pragma unroll
        for (int k = 0; k < 11; ++k) {
            float wk = w[k];
#pragma unroll
            for (int j = 0; j < 8; ++j) {
                float a = h[j + k], bb = s[j + k];
                float u = wk * a, v = wk * bb;
                m1[j] += u;      m2[j] += v;
                x2[j] += u * a;  y2[j] += v * bb;  xy[j] += u * bb;
            }
        }
        *(float4*)&hf[0][r][c0]   = make_float4(m1[0],m1[1],m1[2],m1[3]);
        *(float4*)&hf[0][r][c0+4] = make_float4(m1[4],m1[5],m1[6],m1[7]);
        *(float4*)&hf[1][r][c0]   = make_float4(m2[0],m2[1],m2[2],m2[3]);
        *(float4*)&hf[1][r][c0+4] = make_float4(m2[4],m2[5],m2[6],m2[7]);
        *(float4*)&hf[2][r][c0]   = make_float4(x2[0],x2[1],x2[2],x2[3]);
        *(float4*)&hf[2][r][c0+4] = make_float4(x2[4],x2[5],x2[6],x2[7]);
        *(float4*)&hf[3][r][c0]   = make_float4(y2[0],y2[1],y2[2],y2[3]);
        *(float4*)&hf[3][r][c0+4] = make_float4(y2[4],y2[5],y2[6],y2[7]);
        *(float4*)&hf[4][r][c0]   = make_float4(xy[0],xy[1],xy[2],xy[3]);
        *(float4*)&hf[4][r][c0+4] = make_float4(xy[4],xy[5],xy[6],xy[7]);
    }
    __syncthreads();

    // ---------- Phase 2: vertical 11-tap, 8-row strips, all 256 threads ----------
    const float C1 = 1e-4f, C2 = 9e-4f;
    float local = 0.f;
    {
        int c  = t & 31;
        int r0 = (t >> 5) * 8;    // 0,8,...,56

        float am1[8], am2[8], ax2[8], ay2[8], axy[8];
#pragma unroll
        for (int j = 0; j < 8; ++j) { am1[j]=0.f; am2[j]=0.f; ax2[j]=0.f; ay2[j]=0.f; axy[j]=0.f; }

#pragma unroll
        for (int i = 0; i < 18; ++i) {
            float vm1 = hf[0][r0 + i][c];
            float vm2 = hf[1][r0 + i][c];
            float vx2 = hf[2][r0 + i][c];
            float vy2 = hf[3][r0 + i][c];
            float vxy = hf[4][r0 + i][c];
#pragma unroll
            for (int j = 0; j < 8; ++j) {
                int k = i - j;                 // resolved at compile time
                if (k >= 0 && k <= 10) {
                    float wk = w[k];
                    am1[j] += wk * vm1;  am2[j] += wk * vm2;
                    ax2[j] += wk * vx2;  ay2[j] += wk * vy2;
                    axy[j] += wk * vxy;
                }
            }
        }

        int ox = x0 + c;
#pragma unroll
        for (int j = 0; j < 8; ++j) {
            int oy = y0 + r0 + j;
            if (oy < OUT_W && ox < OUT_W) {
                float m1 = am1[j], m2 = am2[j];
                float mu1s = m1 * m1, mu2s = m2 * m2, m12 = m1 * m2;
                float s1 = ax2[j] - mu1s, s2 = ay2[j] - mu2s, s12 = axy[j] - m12;
                float num = (2.f * m12 + C1) * (2.f * s12 + C2);
                float den = (mu1s + mu2s + C1) * (s1 + s2 + C2);
                local += num / den;
            }
        }
    }

    // ---------- Reduction: wave shuffle + tiny LDS + one atomic ----------
#pragma unroll
    for (int off = 32; off > 0; off >>= 1)
        local += __shfl_down(local, off);
    if ((t & 63) == 0) red[t >> 6] = local;
    __syncthreads();
    if (t == 0) {
        float blocksum = red[0] + red[1] + red[2] + red[3];
        atomicAdd(out, blocksum * (1.0f / (16.0f * 502.0f * 502.0f)));
    }
}

extern "C" void kernel_launch(void* const* d_in, const int* in_sizes, int n_in,
                              void* d_out, int out_size, void* d_ws, size_t ws_size,
                              hipStream_t stream)
{
    const float* sr = (const float*)d_in[0];  // sr_image
    const float* hr = (const float*)d_in[1];  // hr_image
    float* out = (float*)d_out;

    hipMemsetAsync(out, 0, sizeof(float), stream);   // atomic accumulator base

    dim3 grid(16, 8, 16);   // x tiles, y tiles, batch
    ssim_main_kernel<<<grid, 256, 0, stream>>>(sr, hr, out);
}